// Round 11
// baseline (188.434 us; speedup 1.0000x reference)
//
#include <hip/hip_runtime.h>
#include <hip/hip_bf16.h>

typedef __attribute__((ext_vector_type(8))) short short8;
typedef __attribute__((ext_vector_type(4))) float floatx4;

#define L2E 1.4426950408889634f

#if __has_builtin(__builtin_amdgcn_exp2f)
#define EXP2(x) __builtin_amdgcn_exp2f(x)
#else
#define EXP2(x) exp2f(x)
#endif
#if __has_builtin(__builtin_amdgcn_rcpf)
#define RCP(x) __builtin_amdgcn_rcpf(x)
#else
#define RCP(x) (1.0f / (x))
#endif

static __device__ __forceinline__ unsigned short f2bf(float f) {
    unsigned int u = __builtin_bit_cast(unsigned int, f);
    u += 0x7fffu + ((u >> 16) & 1u);   // RNE
    return (unsigned short)(u >> 16);
}
static __device__ __forceinline__ unsigned int pk_bf16(float a, float b) {
    __hip_bfloat162 h2 = __float22bfloat162_rn(make_float2(a, b));   // v_cvt_pk_bf16_f32
    unsigned int u;
    __builtin_memcpy(&u, &h2, 4);     // low16 = a, high16 = b
    return u;
}
static __device__ __forceinline__ short8 pack8(const float* v) {
    unsigned int u[4];
    u[0] = pk_bf16(v[0], v[1]); u[1] = pk_bf16(v[2], v[3]);
    u[2] = pk_bf16(v[4], v[5]); u[3] = pk_bf16(v[6], v[7]);
    short8 s;
    __builtin_memcpy(&s, u, 16);
    return s;
}
static __device__ __forceinline__ void atomf(float* p, float v) {
    __hip_atomic_fetch_add(p, v, __ATOMIC_RELAXED, __HIP_MEMORY_SCOPE_AGENT);
}

// ---------------- 1) QKV GEMM: fp32 inputs, on-the-fly bf16; epilogue zeroes Of/lf ----------------
// qkv[n][o] = sum_c x[c][n] * qw[o][c];  q,k -> [head][n][32], v -> [head][32][n]
__global__ __launch_bounds__(256) void k_qkv(const float* __restrict__ x,
                                             const float* __restrict__ qw,
                                             unsigned short* __restrict__ qm,
                                             unsigned short* __restrict__ km,
                                             unsigned short* __restrict__ vt,
                                             float4* __restrict__ Of4,
                                             float4* __restrict__ lf4) {
    const int tid = threadIdx.x;
    const int wave = tid >> 6, lane = tid & 63;
    const int l16 = lane & 15, quad = lane >> 4;
    const int m0 = blockIdx.x * 64 + wave * 16;   // token rows
    const int o0 = blockIdx.y * 64;               // output channels (of 768)

    floatx4 acc[4] = {};
    #pragma unroll
    for (int cc = 0; cc < 8; ++cc) {
        const int c0 = cc * 32;
        // A-frag: A[m=l16][k=quad*8+j] = x[(c0+quad*8+j)*4096 + m0+l16]
        float av[8];
        const float* xp = x + (size_t)(c0 + quad * 8) * 4096 + m0 + l16;
        #pragma unroll
        for (int j = 0; j < 8; ++j) av[j] = xp[(size_t)j * 4096];
        const short8 a = pack8(av);
        #pragma unroll
        for (int t4 = 0; t4 < 4; ++t4) {
            // B-frag: B[k=quad*8+j][n=l16] = qw[(o0+t4*16+l16)*256 + c0+quad*8+j]
            const float4* bp = reinterpret_cast<const float4*>(
                qw + (size_t)(o0 + t4 * 16 + l16) * 256 + c0 + quad * 8);
            const float4 b0 = bp[0], b1 = bp[1];
            const float bv[8] = {b0.x, b0.y, b0.z, b0.w, b1.x, b1.y, b1.z, b1.w};
            const short8 b = pack8(bv);
            acc[t4] = __builtin_amdgcn_mfma_f32_16x16x32_bf16(a, b, acc[t4], 0, 0, 0);
        }
    }
    #pragma unroll
    for (int t4 = 0; t4 < 4; ++t4) {
        #pragma unroll
        for (int r = 0; r < 4; ++r) {
            const int n = m0 + quad * 4 + r;
            const int o = o0 + t4 * 16 + l16;
            const unsigned short val = f2bf(acc[t4][r]);
            const int s = o >> 8, rem = o & 255, head = rem >> 5, t = rem & 31;
            if (s == 0)       qm[((size_t)head * 4096 + n) * 32 + t] = val;
            else if (s == 1)  km[((size_t)head * 4096 + n) * 32 + t] = val;
            else              vt[((size_t)head * 32 + t) * 4096 + n] = val;
        }
    }
    // zero Of (262144 float4) + lf (8192 float4) across the 768 blocks
    const int gi = (blockIdx.y * 64 + blockIdx.x) * 256 + tid;   // 0..196607
    const float4 zz = make_float4(0.f, 0.f, 0.f, 0.f);
    Of4[gi] = zz;
    if (gi < 65536) Of4[gi + 196608] = zz;
    if (gi < 8192)  lf4[gi] = zz;
}

// ---------------- 2) flash attention: paired heads, no-max softmax, atomic split-K=8 ----------------
__global__ __launch_bounds__(256) void k_attn(const unsigned short* __restrict__ qm,
                                              const unsigned short* __restrict__ km,
                                              const unsigned short* __restrict__ vt,
                                              float* __restrict__ Of,
                                              float* __restrict__ lf) {
    const int h0 = blockIdx.y;          // heads h0 and h0+4
    const int h1 = h0 + 4;
    const int n0 = blockIdx.x * 64;
    const int z  = blockIdx.z;          // 0..7
    const int tid = threadIdx.x;
    const int wave = tid >> 6, lane = tid & 63;
    const int l16 = lane & 15, quad = lane >> 4;
    const int m0 = n0 + wave * 16;

    __shared__ __align__(16) unsigned short pbuf[4][2][16][72];

    const short8 a_q0 = *reinterpret_cast<const short8*>(qm + ((size_t)h0 * 4096 + m0 + l16) * 32 + quad * 8);
    const short8 a_q1 = *reinterpret_cast<const short8*>(qm + ((size_t)h1 * 4096 + m0 + l16) * 32 + quad * 8);

    const int hq = (m0 >> 4) & 15, dq = m0 >> 8;
    float dw2[4];
    #pragma unroll
    for (int r = 0; r < 4; ++r) {
        const float dw = (float)(quad * 4 + r - l16);
        dw2[r] = dw * dw;
    }

    float l0[4] = {0.f, 0.f, 0.f, 0.f}, l1[4] = {0.f, 0.f, 0.f, 0.f};
    floatx4 oa0[2] = {}, oa1[2] = {};
    const float scale2 = 0.17677669529663687f * L2E;   // (1/sqrt(32)) * log2(e)

    for (int it = 0; it < 8; ++it) {
        const int j0 = (n0 + (it * 8 + z) * 64) & 4095;   // interleaved split-K
        const int dk = j0 >> 8, hk0 = (j0 >> 4) & 15;
        const int dd = dq - dk;
        int dh_min = 0;
        if (hq < hk0) dh_min = hk0 - hq;
        else if (hq > hk0 + 3) dh_min = hq - hk0 - 3;
        if (dd * dd + dh_min * dh_min >= 100) continue;   // whole-tile skip (mask is head-indep)

        int thr[4];
        #pragma unroll
        for (int t4 = 0; t4 < 4; ++t4) {
            const int dh = hq - (hk0 + t4);
            thr[t4] = 100 - dd * dd - dh * dh;
        }

        #pragma unroll
        for (int t4 = 0; t4 < 4; ++t4) {
            const bool sib = (thr[t4 ^ 1] > 0);
            if (thr[t4] > 0) {
                const size_t kb = ((size_t)h0 * 4096 + j0 + t4 * 16 + l16) * 32 + quad * 8;
                const short8 b_k0 = *reinterpret_cast<const short8*>(km + kb);
                const short8 b_k1 = *reinterpret_cast<const short8*>(km + kb + 4096 * 4 * 32);
                const floatx4 sf0 = __builtin_amdgcn_mfma_f32_16x16x32_bf16(
                    a_q0, b_k0, (floatx4){0.f, 0.f, 0.f, 0.f}, 0, 0, 0);
                const floatx4 sf1 = __builtin_amdgcn_mfma_f32_16x16x32_bf16(
                    a_q1, b_k1, (floatx4){0.f, 0.f, 0.f, 0.f}, 0, 0, 0);
                const float thrf = (float)thr[t4];
                float p0[4], p1[4];
                #pragma unroll
                for (int r = 0; r < 4; ++r) {
                    const bool live = (dw2[r] < thrf);
                    p0[r] = live ? EXP2(sf0[r] * scale2) : 0.f;
                    p1[r] = live ? EXP2(sf1[r] * scale2) : 0.f;
                    l0[r] += p0[r];
                    l1[r] += p1[r];
                }
                const unsigned int a01 = pk_bf16(p0[0], p0[1]), a23 = pk_bf16(p0[2], p0[3]);
                const unsigned int b01 = pk_bf16(p1[0], p1[1]), b23 = pk_bf16(p1[2], p1[3]);
                const int col = t4 * 16 + l16;
                pbuf[wave][0][quad * 4 + 0][col] = (unsigned short)a01;
                pbuf[wave][0][quad * 4 + 1][col] = (unsigned short)(a01 >> 16);
                pbuf[wave][0][quad * 4 + 2][col] = (unsigned short)a23;
                pbuf[wave][0][quad * 4 + 3][col] = (unsigned short)(a23 >> 16);
                pbuf[wave][1][quad * 4 + 0][col] = (unsigned short)b01;
                pbuf[wave][1][quad * 4 + 1][col] = (unsigned short)(b01 >> 16);
                pbuf[wave][1][quad * 4 + 2][col] = (unsigned short)b23;
                pbuf[wave][1][quad * 4 + 3][col] = (unsigned short)(b23 >> 16);
            } else if (sib) {
                const int col = t4 * 16 + l16;
                #pragma unroll
                for (int r = 0; r < 4; ++r) {
                    pbuf[wave][0][quad * 4 + r][col] = 0;
                    pbuf[wave][1][quad * 4 + r][col] = 0;
                }
            }
        }

        #pragma unroll
        for (int kt = 0; kt < 2; ++kt) {
            if (thr[2 * kt] <= 0 && thr[2 * kt + 1] <= 0) continue;
            const short8 a_p0 = *reinterpret_cast<const short8*>(&pbuf[wave][0][l16][kt * 32 + quad * 8]);
            const short8 a_p1 = *reinterpret_cast<const short8*>(&pbuf[wave][1][l16][kt * 32 + quad * 8]);
            #pragma unroll
            for (int tt = 0; tt < 2; ++tt) {
                const size_t vb = ((size_t)h0 * 32 + tt * 16 + l16) * 4096 + j0 + kt * 32 + quad * 8;
                const short8 b_v0 = *reinterpret_cast<const short8*>(vt + vb);
                const short8 b_v1 = *reinterpret_cast<const short8*>(vt + vb + (size_t)4 * 32 * 4096);
                oa0[tt] = __builtin_amdgcn_mfma_f32_16x16x32_bf16(a_p0, b_v0, oa0[tt], 0, 0, 0);
                oa1[tt] = __builtin_amdgcn_mfma_f32_16x16x32_bf16(a_p1, b_v1, oa1[tt], 0, 0, 0);
            }
        }
    }

    #pragma unroll
    for (int r = 0; r < 4; ++r) {
        #pragma unroll
        for (int off = 1; off < 16; off <<= 1) {
            l0[r] += __shfl_xor(l0[r], off);
            l1[r] += __shfl_xor(l1[r], off);
        }
    }
    if (l16 == 0) {
        #pragma unroll
        for (int r = 0; r < 4; ++r) {
            atomf(&lf[(size_t)h0 * 4096 + m0 + quad * 4 + r], l0[r]);
            atomf(&lf[(size_t)h1 * 4096 + m0 + quad * 4 + r], l1[r]);
        }
    }
    #pragma unroll
    for (int r = 0; r < 4; ++r) {
        const int n = m0 + quad * 4 + r;
        #pragma unroll
        for (int tt = 0; tt < 2; ++tt) {
            atomf(&Of[(size_t)n * 256 + h0 * 32 + tt * 16 + l16], oa0[tt][r]);
            atomf(&Of[(size_t)n * 256 + h1 * 32 + tt * 16 + l16], oa1[tt][r]);
        }
    }
}

// ---------------- 3) proj GEMM + fused normalize + bias: out[o][n] fp32 ----------------
__global__ __launch_bounds__(256) void k_proj(const float* __restrict__ Of,
                                              const float* __restrict__ lf,
                                              const float* __restrict__ pw,
                                              const float* __restrict__ pb,
                                              float* __restrict__ out) {
    const int tid = threadIdx.x;
    const int wave = tid >> 6, lane = tid & 63;
    const int l16 = lane & 15, quad = lane >> 4;
    const int n0 = blockIdx.x * 64;
    const int m0 = blockIdx.y * 64 + wave * 16;   // output channels

    floatx4 acc[4] = {};
    #pragma unroll
    for (int cc = 0; cc < 8; ++cc) {              // head h == cc
        const int c0 = cc * 32;
        // A-frag from pw fp32: row m0+l16, cols c0+quad*8..+7
        const float4* ap = reinterpret_cast<const float4*>(
            pw + (size_t)(m0 + l16) * 256 + c0 + quad * 8);
        const float4 a0 = ap[0], a1 = ap[1];
        const float avv[8] = {a0.x, a0.y, a0.z, a0.w, a1.x, a1.y, a1.z, a1.w};
        const short8 a = pack8(avv);
        #pragma unroll
        for (int t4 = 0; t4 < 4; ++t4) {
            const int n = n0 + t4 * 16 + l16;
            const float inv = RCP(lf[(size_t)cc * 4096 + n]);
            const float4* bp = reinterpret_cast<const float4*>(
                Of + (size_t)n * 256 + c0 + quad * 8);
            const float4 b0 = bp[0], b1 = bp[1];
            const float bvv[8] = {b0.x * inv, b0.y * inv, b0.z * inv, b0.w * inv,
                                  b1.x * inv, b1.y * inv, b1.z * inv, b1.w * inv};
            const short8 b = pack8(bvv);
            acc[t4] = __builtin_amdgcn_mfma_f32_16x16x32_bf16(a, b, acc[t4], 0, 0, 0);
        }
    }
    #pragma unroll
    for (int t4 = 0; t4 < 4; ++t4) {
        #pragma unroll
        for (int r = 0; r < 4; ++r) {
            const int o = m0 + quad * 4 + r;
            const int n = n0 + t4 * 16 + l16;
            out[(size_t)o * 4096 + n] = acc[t4][r] + pb[o];
        }
    }
}

extern "C" void kernel_launch(void* const* d_in, const int* in_sizes, int n_in,
                              void* d_out, int out_size, void* d_ws, size_t ws_size,
                              hipStream_t stream) {
    const float* x      = (const float*)d_in[0];   // [1,256,16,16,16] fp32
    const float* qkv_w  = (const float*)d_in[1];   // [768,256] fp32
    const float* proj_w = (const float*)d_in[2];   // [256,256] fp32
    const float* proj_b = (const float*)d_in[3];   // [256] fp32
    float* out = (float*)d_out;                    // [256,4096] fp32

    char* B = (char*)d_ws;
    const size_t MB = 1u << 20;
    // layout (peak 10.125 MB, within the proven-good 10.625 MB):
    // [0,4)       Of   fp32 [4096][256] accumulator (zeroed by k_qkv epilogue)
    // [4,6)       qm   bf16 [8][4096][32]
    // [6,8)       km   bf16 [8][4096][32]
    // [8,10)      vt   bf16 [8][32][4096]
    // [10,10.125) lf   fp32 [8][4096]
    float*          Of = (float*)(B);
    unsigned short* qm = (unsigned short*)(B + 4 * MB);
    unsigned short* km = (unsigned short*)(B + 6 * MB);
    unsigned short* vt = (unsigned short*)(B + 8 * MB);
    float*          lf = (float*)(B + 10 * MB);

    k_qkv<<<dim3(64, 12), 256, 0, stream>>>(x, qkv_w, qm, km, vt, (float4*)Of, (float4*)lf);
    k_attn<<<dim3(64, 4, 8), 256, 0, stream>>>(qm, km, vt, Of, lf);
    k_proj<<<dim3(64, 4), 256, 0, stream>>>(Of, lf, proj_w, proj_b, out);
}

// Round 12
// 182.473 us; speedup vs baseline: 1.0327x; 1.0327x over previous
//
#include <hip/hip_runtime.h>
#include <hip/hip_bf16.h>

typedef __attribute__((ext_vector_type(8))) short short8;
typedef __attribute__((ext_vector_type(8))) unsigned short ushort8;
typedef __attribute__((ext_vector_type(4))) unsigned short ushort4v;
typedef __attribute__((ext_vector_type(4))) float floatx4;

#define L2E 1.4426950408889634f

#if __has_builtin(__builtin_amdgcn_exp2f)
#define EXP2(x) __builtin_amdgcn_exp2f(x)
#else
#define EXP2(x) exp2f(x)
#endif
#if __has_builtin(__builtin_amdgcn_rcpf)
#define RCP(x) __builtin_amdgcn_rcpf(x)
#else
#define RCP(x) (1.0f / (x))
#endif

static __device__ __forceinline__ float bf2f(unsigned short u) {
    unsigned int v = ((unsigned int)u) << 16;
    return __builtin_bit_cast(float, v);
}
static __device__ __forceinline__ unsigned short f2bf(float f) {
    unsigned int u = __builtin_bit_cast(unsigned int, f);
    u += 0x7fffu + ((u >> 16) & 1u);   // RNE
    return (unsigned short)(u >> 16);
}
static __device__ __forceinline__ unsigned int pk_bf16(float a, float b) {
    __hip_bfloat162 h2 = __float22bfloat162_rn(make_float2(a, b));   // v_cvt_pk_bf16_f32
    unsigned int u;
    __builtin_memcpy(&u, &h2, 4);     // low16 = a, high16 = b
    return u;
}
static __device__ __forceinline__ void atomf(float* p, float v) {
    __hip_atomic_fetch_add(p, v, __ATOMIC_RELAXED, __HIP_MEMORY_SCOPE_AGENT);
}

// ---------------- 1) prep: transpose+cast x, convert weights ----------------
__global__ __launch_bounds__(256) void k_prep(const float* __restrict__ x,
                                              const float* __restrict__ qw,
                                              const float* __restrict__ pw,
                                              unsigned short* __restrict__ tokT,
                                              unsigned short* __restrict__ wqb,
                                              unsigned short* __restrict__ wpb) {
    __shared__ unsigned short tile[64][72];
    const int b = blockIdx.x, tid = threadIdx.x;
    if (b < 256) {            // transpose x[256][4096] -> tokT[4096][256] bf16
        const int n0 = (b & 63) * 64, c0 = (b >> 6) * 64;
        {
            const int c_l = tid >> 2, nl0 = (tid & 3) * 16;
            const float4* src = reinterpret_cast<const float4*>(x + (size_t)(c0 + c_l) * 4096 + n0 + nl0);
            #pragma unroll
            for (int v = 0; v < 4; ++v) {
                const float4 f = src[v];
                tile[c_l][nl0 + v * 4 + 0] = f2bf(f.x);
                tile[c_l][nl0 + v * 4 + 1] = f2bf(f.y);
                tile[c_l][nl0 + v * 4 + 2] = f2bf(f.z);
                tile[c_l][nl0 + v * 4 + 3] = f2bf(f.w);
            }
        }
        __syncthreads();
        {
            const int n_l = tid >> 2, cl0 = (tid & 3) * 16;
            ushort8 a, c;
            #pragma unroll
            for (int i = 0; i < 8; ++i) {
                a[i] = tile[cl0 + i][n_l];
                c[i] = tile[cl0 + 8 + i][n_l];
            }
            ushort8* dst = reinterpret_cast<ushort8*>(tokT + (size_t)(n0 + n_l) * 256 + c0 + cl0);
            dst[0] = a;
            dst[1] = c;
        }
    } else if (b < 448) {     // cvt qkv_w
        const int i = (b - 256) * 256 + tid;
        const float4 v = reinterpret_cast<const float4*>(qw)[i];
        ushort4v o;
        o[0] = f2bf(v.x); o[1] = f2bf(v.y); o[2] = f2bf(v.z); o[3] = f2bf(v.w);
        reinterpret_cast<ushort4v*>(wqb)[i] = o;
    } else {                  // cvt proj_w
        const int i = (b - 448) * 256 + tid;
        const float4 v = reinterpret_cast<const float4*>(pw)[i];
        ushort4v o;
        o[0] = f2bf(v.x); o[1] = f2bf(v.y); o[2] = f2bf(v.z); o[3] = f2bf(v.w);
        reinterpret_cast<ushort4v*>(wpb)[i] = o;
    }
}

// ---------------- 2) QKV GEMM (bf16 inputs); epilogue zeroes Of/lf ----------------
__global__ __launch_bounds__(256) void k_qkv(const unsigned short* __restrict__ tokT,
                                             const unsigned short* __restrict__ w,
                                             unsigned short* __restrict__ qm,
                                             unsigned short* __restrict__ km,
                                             unsigned short* __restrict__ vt,
                                             float4* __restrict__ Of4,
                                             float4* __restrict__ lf4) {
    const int tid = threadIdx.x;
    const int wave = tid >> 6, lane = tid & 63;
    const int l16 = lane & 15, quad = lane >> 4;
    const int m0 = blockIdx.x * 64 + wave * 16;
    const int o0 = blockIdx.y * 64;

    floatx4 acc[4] = {};
    #pragma unroll
    for (int cc = 0; cc < 8; ++cc) {
        const int c0 = cc * 32;
        short8 a = *reinterpret_cast<const short8*>(tokT + (size_t)(m0 + l16) * 256 + c0 + quad * 8);
        #pragma unroll
        for (int t4 = 0; t4 < 4; ++t4) {
            short8 b = *reinterpret_cast<const short8*>(w + (size_t)(o0 + t4 * 16 + l16) * 256 + c0 + quad * 8);
            acc[t4] = __builtin_amdgcn_mfma_f32_16x16x32_bf16(a, b, acc[t4], 0, 0, 0);
        }
    }
    #pragma unroll
    for (int t4 = 0; t4 < 4; ++t4) {
        #pragma unroll
        for (int r = 0; r < 4; ++r) {
            const int n = m0 + quad * 4 + r;
            const int o = o0 + t4 * 16 + l16;
            const unsigned short val = f2bf(acc[t4][r]);
            const int s = o >> 8, rem = o & 255, head = rem >> 5, t = rem & 31;
            if (s == 0)       qm[((size_t)head * 4096 + n) * 32 + t] = val;
            else if (s == 1)  km[((size_t)head * 4096 + n) * 32 + t] = val;
            else              vt[((size_t)head * 32 + t) * 4096 + n] = val;
        }
    }
    // zero Of (262144 float4) + lf (8192 float4); Of overlays nothing live
    const int gi = (blockIdx.y * 64 + blockIdx.x) * 256 + tid;   // 0..196607
    const float4 zz = make_float4(0.f, 0.f, 0.f, 0.f);
    Of4[gi] = zz;
    if (gi < 65536) Of4[gi + 196608] = zz;
    if (gi < 8192)  lf4[gi] = zz;
}

// ---------------- 3) flash attention: no-max softmax, balanced live-tile split-K=8 ----------------
__global__ __launch_bounds__(256) void k_attn(const unsigned short* __restrict__ qm,
                                              const unsigned short* __restrict__ km,
                                              const unsigned short* __restrict__ vt,
                                              float* __restrict__ Of,
                                              float* __restrict__ lf) {
    const int h  = blockIdx.y;
    const int n0 = blockIdx.x * 64;
    const int z  = blockIdx.z;          // 0..7
    const int tid = threadIdx.x;
    const int wave = tid >> 6, lane = tid & 63;
    const int l16 = lane & 15, quad = lane >> 4;
    const int m0 = n0 + wave * 16;

    __shared__ __align__(16) unsigned short pbuf[4][16][72];

    const short8 a_q = *reinterpret_cast<const short8*>(qm + ((size_t)h * 4096 + m0 + l16) * 32 + quad * 8);

    const int hq = (m0 >> 4) & 15, dq = m0 >> 8;
    float dw2[4];
    #pragma unroll
    for (int r = 0; r < 4; ++r) {
        const float dw = (float)(quad * 4 + r - l16);
        dw2[r] = dw * dw;
    }

    float l_acc[4] = {0.f, 0.f, 0.f, 0.f};
    floatx4 o_acc[2] = {};
    const float scale2 = 0.17677669529663687f * L2E;   // (1/sqrt(32)) * log2(e)

    int c = 0;                 // live-tile counter: balanced round-robin over z
    for (int jt = 0; jt < 64; ++jt) {
        const int j0 = jt * 64;
        const int dk = j0 >> 8, hk0 = (j0 >> 4) & 15;
        const int dd = dq - dk;
        int dh_min = 0;
        if (hq < hk0) dh_min = hk0 - hq;
        else if (hq > hk0 + 3) dh_min = hq - hk0 - 3;
        if (dd * dd + dh_min * dh_min >= 100) continue;   // dead tile
        if (((c++) & 7) != z) continue;                   // not my share

        int thr[4];
        #pragma unroll
        for (int t4 = 0; t4 < 4; ++t4) {
            const int dh = hq - (hk0 + t4);
            thr[t4] = 100 - dd * dd - dh * dh;
        }

        #pragma unroll
        for (int t4 = 0; t4 < 4; ++t4) {
            const bool sib = (thr[t4 ^ 1] > 0);
            if (thr[t4] > 0) {
                const short8 b_k = *reinterpret_cast<const short8*>(
                    km + ((size_t)h * 4096 + j0 + t4 * 16 + l16) * 32 + quad * 8);
                const floatx4 sf = __builtin_amdgcn_mfma_f32_16x16x32_bf16(
                    a_q, b_k, (floatx4){0.f, 0.f, 0.f, 0.f}, 0, 0, 0);
                const float thrf = (float)thr[t4];
                float p[4];
                #pragma unroll
                for (int r = 0; r < 4; ++r) {
                    p[r] = (dw2[r] < thrf) ? EXP2(sf[r] * scale2) : 0.f;
                    l_acc[r] += p[r];
                }
                const unsigned int u01 = pk_bf16(p[0], p[1]);
                const unsigned int u23 = pk_bf16(p[2], p[3]);
                const int col = t4 * 16 + l16;
                pbuf[wave][quad * 4 + 0][col] = (unsigned short)u01;
                pbuf[wave][quad * 4 + 1][col] = (unsigned short)(u01 >> 16);
                pbuf[wave][quad * 4 + 2][col] = (unsigned short)u23;
                pbuf[wave][quad * 4 + 3][col] = (unsigned short)(u23 >> 16);
            } else if (sib) {
                const int col = t4 * 16 + l16;
                #pragma unroll
                for (int r = 0; r < 4; ++r) pbuf[wave][quad * 4 + r][col] = 0;
            }
        }

        #pragma unroll
        for (int kt = 0; kt < 2; ++kt) {
            if (thr[2 * kt] <= 0 && thr[2 * kt + 1] <= 0) continue;
            const short8 a_p = *reinterpret_cast<const short8*>(&pbuf[wave][l16][kt * 32 + quad * 8]);
            #pragma unroll
            for (int tt = 0; tt < 2; ++tt) {
                const short8 b_v = *reinterpret_cast<const short8*>(
                    vt + ((size_t)h * 32 + tt * 16 + l16) * 4096 + j0 + kt * 32 + quad * 8);
                o_acc[tt] = __builtin_amdgcn_mfma_f32_16x16x32_bf16(a_p, b_v, o_acc[tt], 0, 0, 0);
            }
        }
    }

    #pragma unroll
    for (int r = 0; r < 4; ++r) {
        #pragma unroll
        for (int off = 1; off < 16; off <<= 1) l_acc[r] += __shfl_xor(l_acc[r], off);
    }
    if (l16 == 0) {
        #pragma unroll
        for (int r = 0; r < 4; ++r)
            atomf(&lf[(size_t)h * 4096 + m0 + quad * 4 + r], l_acc[r]);
    }
    #pragma unroll
    for (int r = 0; r < 4; ++r) {
        const int n = m0 + quad * 4 + r;
        #pragma unroll
        for (int tt = 0; tt < 2; ++tt)
            atomf(&Of[(size_t)n * 256 + h * 32 + tt * 16 + l16], o_acc[tt][r]);
    }
}

// ---------------- 3b) normalize: Of/l -> ao bf16 [n][256] ----------------
__global__ __launch_bounds__(256) void k_norm(const float* __restrict__ Of,
                                              const float* __restrict__ lf,
                                              unsigned short* __restrict__ ao) {
    const int gid = blockIdx.x * 256 + threadIdx.x;   // 262144 threads, 4 floats each
    const int n = gid >> 6, c4 = (gid & 63) * 4, h = c4 >> 5;
    const float inv = RCP(lf[(size_t)h * 4096 + n]);
    const float4 v = reinterpret_cast<const float4*>(Of)[gid];
    ushort4v o;
    o[0] = f2bf(v.x * inv); o[1] = f2bf(v.y * inv);
    o[2] = f2bf(v.z * inv); o[3] = f2bf(v.w * inv);
    *reinterpret_cast<ushort4v*>(ao + (size_t)n * 256 + c4) = o;
}

// ---------------- 4) proj GEMM + bias: out[o][n] fp32 ----------------
__global__ __launch_bounds__(256) void k_proj(const unsigned short* __restrict__ ao,
                                              const unsigned short* __restrict__ pw,
                                              const float* __restrict__ pb,
                                              float* __restrict__ out) {
    const int tid = threadIdx.x;
    const int wave = tid >> 6, lane = tid & 63;
    const int l16 = lane & 15, quad = lane >> 4;
    const int n0 = blockIdx.x * 64;
    const int m0 = blockIdx.y * 64 + wave * 16;

    floatx4 acc[4] = {};
    #pragma unroll
    for (int cc = 0; cc < 8; ++cc) {
        const int c0 = cc * 32;
        short8 a = *reinterpret_cast<const short8*>(pw + (size_t)(m0 + l16) * 256 + c0 + quad * 8);
        #pragma unroll
        for (int t4 = 0; t4 < 4; ++t4) {
            short8 b = *reinterpret_cast<const short8*>(ao + (size_t)(n0 + t4 * 16 + l16) * 256 + c0 + quad * 8);
            acc[t4] = __builtin_amdgcn_mfma_f32_16x16x32_bf16(a, b, acc[t4], 0, 0, 0);
        }
    }
    #pragma unroll
    for (int t4 = 0; t4 < 4; ++t4) {
        #pragma unroll
        for (int r = 0; r < 4; ++r) {
            const int o = m0 + quad * 4 + r;
            const int n = n0 + t4 * 16 + l16;
            out[(size_t)o * 4096 + n] = acc[t4][r] + pb[o];
        }
    }
}

extern "C" void kernel_launch(void* const* d_in, const int* in_sizes, int n_in,
                              void* d_out, int out_size, void* d_ws, size_t ws_size,
                              hipStream_t stream) {
    const float* x      = (const float*)d_in[0];
    const float* qkv_w  = (const float*)d_in[1];
    const float* proj_w = (const float*)d_in[2];
    const float* proj_b = (const float*)d_in[3];
    float* out = (float*)d_out;                    // [256,4096] fp32

    char* B = (char*)d_ws;
    const size_t MB = 1u << 20;
    // ws_size proven >= 15.7 MB (R9 ran K=4). Peak here: 14.125 MB, no live overlaps:
    // [0,2) tokT | [2,3.5) wqb | [3.5,4) wpb | [4,6) qm (-> ao after attn)
    // [6,8) km | [8,10) vt | [10,14) Of | [14,14.125) lf
    unsigned short* tokT = (unsigned short*)(B);
    unsigned short* wqb  = (unsigned short*)(B + 2 * MB);
    unsigned short* wpb  = (unsigned short*)(B + 3 * MB + 512 * 1024);
    unsigned short* qm   = (unsigned short*)(B + 4 * MB);
    unsigned short* km   = (unsigned short*)(B + 6 * MB);
    unsigned short* vt   = (unsigned short*)(B + 8 * MB);
    float*          Of   = (float*)(B + 10 * MB);
    float*          lf   = (float*)(B + 14 * MB);
    unsigned short* ao   = (unsigned short*)(B + 4 * MB);   // overlay qm (dead after attn)

    k_prep<<<dim3(512), 256, 0, stream>>>(x, qkv_w, proj_w, tokT, wqb, wpb);
    k_qkv<<<dim3(64, 12), 256, 0, stream>>>(tokT, wqb, qm, km, vt, (float4*)Of, (float4*)lf);
    k_attn<<<dim3(64, 8, 8), 256, 0, stream>>>(qm, km, vt, Of, lf);
    k_norm<<<dim3(1024), 256, 0, stream>>>(Of, lf, ao);
    k_proj<<<dim3(64, 4), 256, 0, stream>>>(ao, wpb, proj_b, out);
}

// Round 13
// 167.082 us; speedup vs baseline: 1.1278x; 1.0921x over previous
//
#include <hip/hip_runtime.h>
#include <hip/hip_bf16.h>

typedef __attribute__((ext_vector_type(8))) short short8;
typedef __attribute__((ext_vector_type(8))) unsigned short ushort8;
typedef __attribute__((ext_vector_type(4))) float floatx4;

#define L2E 1.4426950408889634f

#if __has_builtin(__builtin_amdgcn_exp2f)
#define EXP2(x) __builtin_amdgcn_exp2f(x)
#else
#define EXP2(x) exp2f(x)
#endif
#if __has_builtin(__builtin_amdgcn_rcpf)
#define RCP(x) __builtin_amdgcn_rcpf(x)
#else
#define RCP(x) (1.0f / (x))
#endif

static __device__ __forceinline__ unsigned short f2bf(float f) {
    unsigned int u = __builtin_bit_cast(unsigned int, f);
    u += 0x7fffu + ((u >> 16) & 1u);   // RNE
    return (unsigned short)(u >> 16);
}
static __device__ __forceinline__ unsigned int pk_bf16(float a, float b) {
    __hip_bfloat162 h2 = __float22bfloat162_rn(make_float2(a, b));   // v_cvt_pk_bf16_f32
    unsigned int u;
    __builtin_memcpy(&u, &h2, 4);     // low16 = a, high16 = b
    return u;
}

// ---------------- 1) QKV GEMM, self-staging (transpose x + cvt w in LDS) ----------------
// qkv[n][o] = sum_c x[c][n]*qw[o][c]. q pre-scaled by (1/sqrt(32))*log2(e).
// q,k -> [head][n][32] bf16; v -> [head][32][n] bf16.
__global__ __launch_bounds__(256) void k_qkv(const float* __restrict__ x,
                                             const float* __restrict__ qw,
                                             unsigned short* __restrict__ qm,
                                             unsigned short* __restrict__ km,
                                             unsigned short* __restrict__ vt) {
    __shared__ __align__(16) unsigned short At[64][136];   // [m][c-half] 272B row (16B-aligned)
    __shared__ __align__(16) unsigned short Wt[64][136];   // [o][c-half]
    const int tid = threadIdx.x;
    const int wave = tid >> 6, lane = tid & 63;
    const int l16 = lane & 15, quad = lane >> 4;
    const int m0 = blockIdx.x * 64;               // token block
    const int o0 = blockIdx.y * 64;               // output-channel block (of 768)

    floatx4 acc[4] = {};
    for (int rnd = 0; rnd < 2; ++rnd) {
        const int cbase = rnd * 128;
        if (rnd) __syncthreads();                 // drain reads of previous round
        // stage A (transposed): x[cbase+c_l][m0+moff..+15] -> At[moff..][c_l]
        {
            const int moff = (tid & 3) * 16;
            #pragma unroll
            for (int half = 0; half < 2; ++half) {
                const int c_l = (tid >> 2) + 64 * half;
                const float4* xp = reinterpret_cast<const float4*>(
                    x + (size_t)(cbase + c_l) * 4096 + m0 + moff);
                const float4 f0 = xp[0], f1 = xp[1], f2 = xp[2], f3 = xp[3];
                At[moff +  0][c_l] = f2bf(f0.x); At[moff +  1][c_l] = f2bf(f0.y);
                At[moff +  2][c_l] = f2bf(f0.z); At[moff +  3][c_l] = f2bf(f0.w);
                At[moff +  4][c_l] = f2bf(f1.x); At[moff +  5][c_l] = f2bf(f1.y);
                At[moff +  6][c_l] = f2bf(f1.z); At[moff +  7][c_l] = f2bf(f1.w);
                At[moff +  8][c_l] = f2bf(f2.x); At[moff +  9][c_l] = f2bf(f2.y);
                At[moff + 10][c_l] = f2bf(f2.z); At[moff + 11][c_l] = f2bf(f2.w);
                At[moff + 12][c_l] = f2bf(f3.x); At[moff + 13][c_l] = f2bf(f3.y);
                At[moff + 14][c_l] = f2bf(f3.z); At[moff + 15][c_l] = f2bf(f3.w);
            }
        }
        // stage W (row-major): qw[o0+o_l][cbase+cp..+31] -> Wt[o_l][cp..] (contiguous)
        {
            const int o_l = tid >> 2, cp = (tid & 3) * 32;
            const float4* wp = reinterpret_cast<const float4*>(
                qw + (size_t)(o0 + o_l) * 256 + cbase + cp);
            #pragma unroll
            for (int j = 0; j < 2; ++j) {
                const float4 g0 = wp[4 * j + 0], g1 = wp[4 * j + 1];
                const float4 g2 = wp[4 * j + 2], g3 = wp[4 * j + 3];
                unsigned int u[8];
                u[0] = pk_bf16(g0.x, g0.y); u[1] = pk_bf16(g0.z, g0.w);
                u[2] = pk_bf16(g1.x, g1.y); u[3] = pk_bf16(g1.z, g1.w);
                u[4] = pk_bf16(g2.x, g2.y); u[5] = pk_bf16(g2.z, g2.w);
                u[6] = pk_bf16(g3.x, g3.y); u[7] = pk_bf16(g3.z, g3.w);
                __builtin_memcpy(&Wt[o_l][cp + 16 * j], u, 32);
            }
        }
        __syncthreads();
        // compute: 4 K-steps of 32 over this c-half
        #pragma unroll
        for (int cc = 0; cc < 4; ++cc) {
            const int c0 = cc * 32 + quad * 8;
            const short8 a = *reinterpret_cast<const short8*>(&At[wave * 16 + l16][c0]);
            #pragma unroll
            for (int t4 = 0; t4 < 4; ++t4) {
                const short8 b = *reinterpret_cast<const short8*>(&Wt[t4 * 16 + l16][c0]);
                acc[t4] = __builtin_amdgcn_mfma_f32_16x16x32_bf16(a, b, acc[t4], 0, 0, 0);
            }
        }
    }
    const float qscale = 0.17677669529663687f * L2E;   // folded into q
    #pragma unroll
    for (int t4 = 0; t4 < 4; ++t4) {
        #pragma unroll
        for (int r = 0; r < 4; ++r) {
            const int n = m0 + wave * 16 + quad * 4 + r;
            const int o = o0 + t4 * 16 + l16;
            const int s = o >> 8, rem = o & 255, head = rem >> 5, t = rem & 31;
            if (s == 0)       qm[((size_t)head * 4096 + n) * 32 + t] = f2bf(acc[t4][r] * qscale);
            else if (s == 1)  km[((size_t)head * 4096 + n) * 32 + t] = f2bf(acc[t4][r]);
            else              vt[((size_t)head * 32 + t) * 4096 + n] = f2bf(acc[t4][r]);
        }
    }
}

// ---------------- 2) flash attention: in-block key split, LDS combine, no atomics ----------------
// block = 16 queries x 1 head; 4 waves split live key tiles round-robin; writes ao bf16 [n][256].
__global__ __launch_bounds__(256) void k_attn(const unsigned short* __restrict__ qm,
                                              const unsigned short* __restrict__ km,
                                              const unsigned short* __restrict__ vt,
                                              unsigned short* __restrict__ ao) {
    const int h   = blockIdx.y;
    const int nq0 = blockIdx.x * 16;    // 16 queries, all share (d,h) coords
    const int tid = threadIdx.x;
    const int wv  = __builtin_amdgcn_readfirstlane(tid >> 6);
    const int lane = tid & 63;
    const int l16 = lane & 15, quad = lane >> 4;

    __shared__ __align__(16) unsigned short pbuf[4][16][72];   // per-wave P tile
    __shared__ __align__(16) float obuf[4][16][34];            // per-wave O partials
    __shared__ float lbuf[4][16];                              // per-wave l partials

    const short8 a_q = *reinterpret_cast<const short8*>(
        qm + ((size_t)h * 4096 + nq0 + l16) * 32 + quad * 8);

    const int hq = (nq0 >> 4) & 15, dq = nq0 >> 8;   // block-uniform
    float dw2[4];
    #pragma unroll
    for (int r = 0; r < 4; ++r) {
        const float dw = (float)(quad * 4 + r - l16);
        dw2[r] = dw * dw;
    }

    // per-lane base pointers (loop adds are uniform offsets)
    const unsigned short* kmh = km + ((size_t)h << 17) + l16 * 32 + quad * 8;
    const unsigned short* vt0 = vt + ((size_t)(h * 32 + l16) << 12) + quad * 8;
    const unsigned short* vt1 = vt0 + (16 << 12);

    float l_acc[4] = {0.f, 0.f, 0.f, 0.f};
    floatx4 o_acc[2] = {};

    int c = 0;                          // live-tile round-robin over the 4 waves
    for (int jt = 0; jt < 64; ++jt) {
        const int dk = jt >> 2, hk0 = (jt & 3) * 4;   // scalar scan
        const int dd = dq - dk;
        int dh_min = 0;
        if (hq < hk0) dh_min = hk0 - hq;
        else if (hq > hk0 + 3) dh_min = hq - hk0 - 3;
        if (dd * dd + dh_min * dh_min >= 100) continue;   // dead tile
        if (((c++) & 3) != wv) continue;                  // another wave's share

        const int j0 = jt * 64;
        int thr[4];
        #pragma unroll
        for (int t4 = 0; t4 < 4; ++t4) {
            const int dh = hq - (hk0 + t4);
            thr[t4] = 100 - dd * dd - dh * dh;
        }

        #pragma unroll
        for (int t4 = 0; t4 < 4; ++t4) {
            const bool sib = (thr[t4 ^ 1] > 0);
            if (thr[t4] > 0) {
                const short8 b_k = *reinterpret_cast<const short8*>(kmh + ((j0 + t4 * 16) << 5));
                const floatx4 sf = __builtin_amdgcn_mfma_f32_16x16x32_bf16(
                    a_q, b_k, (floatx4){0.f, 0.f, 0.f, 0.f}, 0, 0, 0);
                const float thrf = (float)thr[t4];
                float p[4];
                #pragma unroll
                for (int r = 0; r < 4; ++r) {
                    p[r] = (dw2[r] < thrf) ? EXP2(sf[r]) : 0.f;   // q pre-scaled
                    l_acc[r] += p[r];
                }
                const unsigned int u01 = pk_bf16(p[0], p[1]);
                const unsigned int u23 = pk_bf16(p[2], p[3]);
                const int col = t4 * 16 + l16;
                pbuf[wv][quad * 4 + 0][col] = (unsigned short)u01;
                pbuf[wv][quad * 4 + 1][col] = (unsigned short)(u01 >> 16);
                pbuf[wv][quad * 4 + 2][col] = (unsigned short)u23;
                pbuf[wv][quad * 4 + 3][col] = (unsigned short)(u23 >> 16);
            } else if (sib) {
                const int col = t4 * 16 + l16;
                #pragma unroll
                for (int r = 0; r < 4; ++r) pbuf[wv][quad * 4 + r][col] = 0;
            }
        }

        #pragma unroll
        for (int kt = 0; kt < 2; ++kt) {
            if (thr[2 * kt] <= 0 && thr[2 * kt + 1] <= 0) continue;
            const short8 a_p = *reinterpret_cast<const short8*>(&pbuf[wv][l16][kt * 32 + quad * 8]);
            const short8 b_v0 = *reinterpret_cast<const short8*>(vt0 + j0 + kt * 32);
            const short8 b_v1 = *reinterpret_cast<const short8*>(vt1 + j0 + kt * 32);
            o_acc[0] = __builtin_amdgcn_mfma_f32_16x16x32_bf16(a_p, b_v0, o_acc[0], 0, 0, 0);
            o_acc[1] = __builtin_amdgcn_mfma_f32_16x16x32_bf16(a_p, b_v1, o_acc[1], 0, 0, 0);
        }
    }

    // per-wave l reduction over the 16 lanes of each quad-row
    #pragma unroll
    for (int r = 0; r < 4; ++r) {
        #pragma unroll
        for (int off = 1; off < 16; off <<= 1) l_acc[r] += __shfl_xor(l_acc[r], off);
    }
    if (l16 == 0) {
        #pragma unroll
        for (int r = 0; r < 4; ++r) lbuf[wv][quad * 4 + r] = l_acc[r];
    }
    #pragma unroll
    for (int r = 0; r < 4; ++r) {
        obuf[wv][quad * 4 + r][l16]      = o_acc[0][r];
        obuf[wv][quad * 4 + r][16 + l16] = o_acc[1][r];
    }
    __syncthreads();

    // combine 4 waves, normalize, write 2 adjacent bf16 per thread
    const int row = tid >> 4, c2 = (tid & 15) * 2;
    const float lt = lbuf[0][row] + lbuf[1][row] + lbuf[2][row] + lbuf[3][row];
    const float inv = RCP(lt);
    const float oa = (obuf[0][row][c2]     + obuf[1][row][c2]     + obuf[2][row][c2]     + obuf[3][row][c2])     * inv;
    const float ob = (obuf[0][row][c2 + 1] + obuf[1][row][c2 + 1] + obuf[2][row][c2 + 1] + obuf[3][row][c2 + 1]) * inv;
    const unsigned int uo = pk_bf16(oa, ob);
    *reinterpret_cast<unsigned int*>(ao + (size_t)(nq0 + row) * 256 + h * 32 + c2) = uo;
}

// ---------------- 3) proj GEMM + bias, self-staging pw: out[o][n] fp32 ----------------
__global__ __launch_bounds__(256) void k_proj(const unsigned short* __restrict__ ao,
                                              const float* __restrict__ pw,
                                              const float* __restrict__ pb,
                                              float* __restrict__ out) {
    __shared__ __align__(16) unsigned short Pt[64][264];   // [o][c], 528B row (16B-aligned)
    const int tid = threadIdx.x;
    const int wave = tid >> 6, lane = tid & 63;
    const int l16 = lane & 15, quad = lane >> 4;
    const int n0 = blockIdx.x * 64;
    const int m0 = blockIdx.y * 64;

    // stage pw rows m0..m0+63 (full K=256) as bf16
    {
        const int o_l = tid >> 2, cp = (tid & 3) * 64;
        const float4* wp = reinterpret_cast<const float4*>(pw + (size_t)(m0 + o_l) * 256 + cp);
        #pragma unroll
        for (int j = 0; j < 4; ++j) {
            const float4 g0 = wp[4 * j + 0], g1 = wp[4 * j + 1];
            const float4 g2 = wp[4 * j + 2], g3 = wp[4 * j + 3];
            unsigned int u[8];
            u[0] = pk_bf16(g0.x, g0.y); u[1] = pk_bf16(g0.z, g0.w);
            u[2] = pk_bf16(g1.x, g1.y); u[3] = pk_bf16(g1.z, g1.w);
            u[4] = pk_bf16(g2.x, g2.y); u[5] = pk_bf16(g2.z, g2.w);
            u[6] = pk_bf16(g3.x, g3.y); u[7] = pk_bf16(g3.z, g3.w);
            __builtin_memcpy(&Pt[o_l][cp + 16 * j], u, 32);
        }
    }
    __syncthreads();

    floatx4 acc[4] = {};
    #pragma unroll
    for (int cc = 0; cc < 8; ++cc) {
        const int c0 = cc * 32 + quad * 8;
        const short8 a = *reinterpret_cast<const short8*>(&Pt[wave * 16 + l16][c0]);
        #pragma unroll
        for (int t4 = 0; t4 < 4; ++t4) {
            const short8 b = *reinterpret_cast<const short8*>(
                ao + (size_t)(n0 + t4 * 16 + l16) * 256 + c0);
            acc[t4] = __builtin_amdgcn_mfma_f32_16x16x32_bf16(a, b, acc[t4], 0, 0, 0);
        }
    }
    #pragma unroll
    for (int t4 = 0; t4 < 4; ++t4) {
        #pragma unroll
        for (int r = 0; r < 4; ++r) {
            const int o = m0 + wave * 16 + quad * 4 + r;
            const int n = n0 + t4 * 16 + l16;
            out[(size_t)o * 4096 + n] = acc[t4][r] + pb[o];
        }
    }
}

extern "C" void kernel_launch(void* const* d_in, const int* in_sizes, int n_in,
                              void* d_out, int out_size, void* d_ws, size_t ws_size,
                              hipStream_t stream) {
    const float* x      = (const float*)d_in[0];   // [1,256,16,16,16] fp32
    const float* qkv_w  = (const float*)d_in[1];   // [768,256] fp32
    const float* proj_w = (const float*)d_in[2];   // [256,256] fp32
    const float* proj_b = (const float*)d_in[3];   // [256] fp32
    float* out = (float*)d_out;                    // [256,4096] fp32

    char* B = (char*)d_ws;
    const size_t MB = 1u << 20;
    // [0,2) ao | [2,4) qm | [4,6) km | [6,8) vt   (8 MB total)
    unsigned short* ao = (unsigned short*)(B);
    unsigned short* qm = (unsigned short*)(B + 2 * MB);
    unsigned short* km = (unsigned short*)(B + 4 * MB);
    unsigned short* vt = (unsigned short*)(B + 6 * MB);

    k_qkv<<<dim3(64, 12), 256, 0, stream>>>(x, qkv_w, qm, km, vt);
    k_attn<<<dim3(256, 8), 256, 0, stream>>>(qm, km, vt, ao);
    k_proj<<<dim3(64, 4), 256, 0, stream>>>(ao, proj_w, proj_b, out);
}

// Round 15
// 166.687 us; speedup vs baseline: 1.1305x; 1.0024x over previous
//
#include <hip/hip_runtime.h>
#include <hip/hip_bf16.h>

typedef __attribute__((ext_vector_type(8))) short short8;
typedef __attribute__((ext_vector_type(8))) unsigned short ushort8;
typedef __attribute__((ext_vector_type(4))) float floatx4;

#define L2E 1.4426950408889634f

#if __has_builtin(__builtin_amdgcn_exp2f)
#define EXP2(x) __builtin_amdgcn_exp2f(x)
#else
#define EXP2(x) exp2f(x)
#endif
#if __has_builtin(__builtin_amdgcn_rcpf)
#define RCP(x) __builtin_amdgcn_rcpf(x)
#else
#define RCP(x) (1.0f / (x))
#endif

static __device__ __forceinline__ unsigned short f2bf(float f) {
    unsigned int u = __builtin_bit_cast(unsigned int, f);
    u += 0x7fffu + ((u >> 16) & 1u);   // RNE
    return (unsigned short)(u >> 16);
}
static __device__ __forceinline__ unsigned int pk_bf16(float a, float b) {
    __hip_bfloat162 h2 = __float22bfloat162_rn(make_float2(a, b));   // v_cvt_pk_bf16_f32
    unsigned int u;
    __builtin_memcpy(&u, &h2, 4);     // low16 = a, high16 = b
    return u;
}

// ---------------- 1) QKV GEMM, self-staging (transpose x + cvt w in LDS) ----------------
__global__ __launch_bounds__(256) void k_qkv(const float* __restrict__ x,
                                             const float* __restrict__ qw,
                                             unsigned short* __restrict__ qm,
                                             unsigned short* __restrict__ km,
                                             unsigned short* __restrict__ vt) {
    __shared__ __align__(16) unsigned short At[64][136];
    __shared__ __align__(16) unsigned short Wt[64][136];
    const int tid = threadIdx.x;
    const int wave = tid >> 6, lane = tid & 63;
    const int l16 = lane & 15, quad = lane >> 4;
    const int m0 = blockIdx.x * 64;
    const int o0 = blockIdx.y * 64;

    floatx4 acc[4] = {};
    for (int rnd = 0; rnd < 2; ++rnd) {
        const int cbase = rnd * 128;
        if (rnd) __syncthreads();
        {
            const int moff = (tid & 3) * 16;
            #pragma unroll
            for (int half = 0; half < 2; ++half) {
                const int c_l = (tid >> 2) + 64 * half;
                const float4* xp = reinterpret_cast<const float4*>(
                    x + (size_t)(cbase + c_l) * 4096 + m0 + moff);
                const float4 f0 = xp[0], f1 = xp[1], f2 = xp[2], f3 = xp[3];
                At[moff +  0][c_l] = f2bf(f0.x); At[moff +  1][c_l] = f2bf(f0.y);
                At[moff +  2][c_l] = f2bf(f0.z); At[moff +  3][c_l] = f2bf(f0.w);
                At[moff +  4][c_l] = f2bf(f1.x); At[moff +  5][c_l] = f2bf(f1.y);
                At[moff +  6][c_l] = f2bf(f1.z); At[moff +  7][c_l] = f2bf(f1.w);
                At[moff +  8][c_l] = f2bf(f2.x); At[moff +  9][c_l] = f2bf(f2.y);
                At[moff + 10][c_l] = f2bf(f2.z); At[moff + 11][c_l] = f2bf(f2.w);
                At[moff + 12][c_l] = f2bf(f3.x); At[moff + 13][c_l] = f2bf(f3.y);
                At[moff + 14][c_l] = f2bf(f3.z); At[moff + 15][c_l] = f2bf(f3.w);
            }
        }
        {
            const int o_l = tid >> 2, cp = (tid & 3) * 32;
            const float4* wp = reinterpret_cast<const float4*>(
                qw + (size_t)(o0 + o_l) * 256 + cbase + cp);
            #pragma unroll
            for (int j = 0; j < 2; ++j) {
                const float4 g0 = wp[4 * j + 0], g1 = wp[4 * j + 1];
                const float4 g2 = wp[4 * j + 2], g3 = wp[4 * j + 3];
                unsigned int u[8];
                u[0] = pk_bf16(g0.x, g0.y); u[1] = pk_bf16(g0.z, g0.w);
                u[2] = pk_bf16(g1.x, g1.y); u[3] = pk_bf16(g1.z, g1.w);
                u[4] = pk_bf16(g2.x, g2.y); u[5] = pk_bf16(g2.z, g2.w);
                u[6] = pk_bf16(g3.x, g3.y); u[7] = pk_bf16(g3.z, g3.w);
                __builtin_memcpy(&Wt[o_l][cp + 16 * j], u, 32);
            }
        }
        __syncthreads();
        #pragma unroll
        for (int cc = 0; cc < 4; ++cc) {
            const int c0 = cc * 32 + quad * 8;
            const short8 a = *reinterpret_cast<const short8*>(&At[wave * 16 + l16][c0]);
            #pragma unroll
            for (int t4 = 0; t4 < 4; ++t4) {
                const short8 b = *reinterpret_cast<const short8*>(&Wt[t4 * 16 + l16][c0]);
                acc[t4] = __builtin_amdgcn_mfma_f32_16x16x32_bf16(a, b, acc[t4], 0, 0, 0);
            }
        }
    }
    const float qscale = 0.17677669529663687f * L2E;
    #pragma unroll
    for (int t4 = 0; t4 < 4; ++t4) {
        #pragma unroll
        for (int r = 0; r < 4; ++r) {
            const int n = m0 + wave * 16 + quad * 4 + r;
            const int o = o0 + t4 * 16 + l16;
            const int s = o >> 8, rem = o & 255, head = rem >> 5, t = rem & 31;
            if (s == 0)       qm[((size_t)head * 4096 + n) * 32 + t] = f2bf(acc[t4][r] * qscale);
            else if (s == 1)  km[((size_t)head * 4096 + n) * 32 + t] = f2bf(acc[t4][r]);
            else              vt[((size_t)head * 32 + t) * 4096 + n] = f2bf(acc[t4][r]);
        }
    }
}

// ---------------- 2) flash attention: S^T form, PT[q][key] LDS transpose, K/V prefetch ----------------
// block = 16 queries x 1 head; 4 waves split live key tiles; no atomics; ao bf16 [n][256].
__global__ __launch_bounds__(256) void k_attn(const unsigned short* __restrict__ qm,
                                              const unsigned short* __restrict__ km,
                                              const unsigned short* __restrict__ vt,
                                              unsigned short* __restrict__ ao) {
    const int h   = blockIdx.y;
    const int nq0 = blockIdx.x * 16;
    const int tid = threadIdx.x;
    const int wv  = tid >> 6;
    const int lane = tid & 63;
    const int l16 = lane & 15, quad = lane >> 4;

    __shared__ __align__(16) unsigned short PT[4][16][72];   // [wave][q][key(64)+pad]
    __shared__ __align__(16) float obuf[4][32][20];          // [wave][d][q]
    __shared__ float lbuf[4][16];

    // B-operand for S^T: Q^T (n=q on l16, k=c on quad*8+j)
    const short8 a_q = *reinterpret_cast<const short8*>(
        qm + ((size_t)h * 4096 + nq0 + l16) * 32 + quad * 8);

    const int hq = (nq0 >> 4) & 15, dq = nq0 >> 8;
    float dw2[4];
    #pragma unroll
    for (int r = 0; r < 4; ++r) {
        const float dw = (float)(quad * 4 + r - l16);   // key_w - q_w (symmetric form)
        dw2[r] = dw * dw;
    }

    const unsigned short* kmh = km + ((size_t)h << 17) + l16 * 32 + quad * 8;
    const unsigned short* vt0 = vt + ((size_t)(h * 32 + l16) << 12) + quad * 8;
    const unsigned short* vt1 = vt0 + (16 << 12);

    float l_acc = 0.f;
    floatx4 o_acc[2] = {};

    int jt = -1, c = 0;
    int j0c = -1, thrc[4];
    short8 kb[4];

#define SCAN(J0, THR)                                                     \
    J0 = -1;                                                              \
    while (++jt < 64) {                                                   \
        const int dk = jt >> 2, hk0 = (jt & 3) * 4;                       \
        const int dd = dq - dk;                                           \
        int dh = 0;                                                       \
        if (hq < hk0) dh = hk0 - hq;                                      \
        else if (hq > hk0 + 3) dh = hq - hk0 - 3;                         \
        if (dd * dd + dh * dh >= 100) continue;                           \
        if (((c++) & 3) != wv) continue;                                  \
        J0 = jt * 64;                                                     \
        const int bb = 100 - dd * dd;                                     \
        THR[0] = bb - (hq - hk0) * (hq - hk0);                            \
        THR[1] = bb - (hq - hk0 - 1) * (hq - hk0 - 1);                    \
        THR[2] = bb - (hq - hk0 - 2) * (hq - hk0 - 2);                    \
        THR[3] = bb - (hq - hk0 - 3) * (hq - hk0 - 3);                    \
        break;                                                            \
    }

    SCAN(j0c, thrc)
    if (j0c >= 0) {
        #pragma unroll
        for (int t4 = 0; t4 < 4; ++t4)
            kb[t4] = *reinterpret_cast<const short8*>(kmh + ((j0c + t4 * 16) << 5));
    }

    while (j0c >= 0) {
        // prefetch next live tile's K
        int j0n, thrn[4];
        SCAN(j0n, thrn)
        short8 kn[4];
        if (j0n >= 0) {
            #pragma unroll
            for (int t4 = 0; t4 < 4; ++t4)
                kn[t4] = *reinterpret_cast<const short8*>(kmh + ((j0n + t4 * 16) << 5));
        }
        // V loads for current (consumed after S/exp)
        const short8 v00 = *reinterpret_cast<const short8*>(vt0 + j0c);
        const short8 v01 = *reinterpret_cast<const short8*>(vt1 + j0c);
        const short8 v10 = *reinterpret_cast<const short8*>(vt0 + j0c + 32);
        const short8 v11 = *reinterpret_cast<const short8*>(vt1 + j0c + 32);

        // S^T = K·Q^T per subtile; p = exp2; lane holds P^T[key=t4*16+quad*4+r][q=l16]
        // -> 4 consecutive bf16 at PT[q][t4*16+quad*4]: one b64 write per subtile
        #pragma unroll
        for (int t4 = 0; t4 < 4; ++t4) {
            const bool sib = (thrc[t4 ^ 1] > 0);
            if (thrc[t4] > 0) {
                const floatx4 sf = __builtin_amdgcn_mfma_f32_16x16x32_bf16(
                    kb[t4], a_q, (floatx4){0.f, 0.f, 0.f, 0.f}, 0, 0, 0);
                const float thrf = (float)thrc[t4];
                const float p0 = (dw2[0] < thrf) ? EXP2(sf[0]) : 0.f;
                const float p1 = (dw2[1] < thrf) ? EXP2(sf[1]) : 0.f;
                const float p2 = (dw2[2] < thrf) ? EXP2(sf[2]) : 0.f;
                const float p3 = (dw2[3] < thrf) ? EXP2(sf[3]) : 0.f;
                l_acc += (p0 + p1) + (p2 + p3);
                unsigned int pair[2];
                pair[0] = pk_bf16(p0, p1);
                pair[1] = pk_bf16(p2, p3);
                __builtin_memcpy(&PT[wv][l16][t4 * 16 + quad * 4], pair, 8);
            } else if (sib) {
                const unsigned int zz[2] = {0u, 0u};
                __builtin_memcpy(&PT[wv][l16][t4 * 16 + quad * 4], zz, 8);
            }
        }

        // PV: O^T += V^T · P^T ; B-frag = b128 read at PT[q=l16][kt*32+quad*8]
        #pragma unroll
        for (int kt = 0; kt < 2; ++kt) {
            if (thrc[2 * kt] <= 0 && thrc[2 * kt + 1] <= 0) continue;
            const short8 b_p = *reinterpret_cast<const short8*>(&PT[wv][l16][kt * 32 + quad * 8]);
            o_acc[0] = __builtin_amdgcn_mfma_f32_16x16x32_bf16(
                kt ? v10 : v00, b_p, o_acc[0], 0, 0, 0);
            o_acc[1] = __builtin_amdgcn_mfma_f32_16x16x32_bf16(
                kt ? v11 : v01, b_p, o_acc[1], 0, 0, 0);
        }

        // rotate
        j0c = j0n;
        #pragma unroll
        for (int t4 = 0; t4 < 4; ++t4) { thrc[t4] = thrn[t4]; kb[t4] = kn[t4]; }
    }
#undef SCAN

    // l: per-lane scalar; sum over quads (lanes sharing l16)
    l_acc += __shfl_xor(l_acc, 16);
    l_acc += __shfl_xor(l_acc, 32);
    if (lane < 16) lbuf[wv][l16] = l_acc;
    #pragma unroll
    for (int tt = 0; tt < 2; ++tt)
        #pragma unroll
        for (int r = 0; r < 4; ++r)
            obuf[wv][tt * 16 + quad * 4 + r][l16] = o_acc[tt][r];
    __syncthreads();

    // combine waves, normalize, write (q = tid&15, d pair = (tid>>4)*2)
    const int q = tid & 15, d0 = (tid >> 4) * 2;
    const float lt = lbuf[0][q] + lbuf[1][q] + lbuf[2][q] + lbuf[3][q];
    const float inv = RCP(lt);
    const float oa = (obuf[0][d0][q] + obuf[1][d0][q] + obuf[2][d0][q] + obuf[3][d0][q]) * inv;
    const float ob = (obuf[0][d0 + 1][q] + obuf[1][d0 + 1][q] + obuf[2][d0 + 1][q] + obuf[3][d0 + 1][q]) * inv;
    const unsigned int uo = pk_bf16(oa, ob);
    *reinterpret_cast<unsigned int*>(ao + (size_t)(nq0 + q) * 256 + h * 32 + d0) = uo;
}

// ---------------- 3) proj GEMM + bias, self-staging pw: out[o][n] fp32 ----------------
__global__ __launch_bounds__(256) void k_proj(const unsigned short* __restrict__ ao,
                                              const float* __restrict__ pw,
                                              const float* __restrict__ pb,
                                              float* __restrict__ out) {
    __shared__ __align__(16) unsigned short Pt[64][264];
    const int tid = threadIdx.x;
    const int wave = tid >> 6, lane = tid & 63;
    const int l16 = lane & 15, quad = lane >> 4;
    const int n0 = blockIdx.x * 64;
    const int m0 = blockIdx.y * 64;

    {
        const int o_l = tid >> 2, cp = (tid & 3) * 64;
        const float4* wp = reinterpret_cast<const float4*>(pw + (size_t)(m0 + o_l) * 256 + cp);
        #pragma unroll
        for (int j = 0; j < 4; ++j) {
            const float4 g0 = wp[4 * j + 0], g1 = wp[4 * j + 1];
            const float4 g2 = wp[4 * j + 2], g3 = wp[4 * j + 3];
            unsigned int u[8];
            u[0] = pk_bf16(g0.x, g0.y); u[1] = pk_bf16(g0.z, g0.w);
            u[2] = pk_bf16(g1.x, g1.y); u[3] = pk_bf16(g1.z, g1.w);
            u[4] = pk_bf16(g2.x, g2.y); u[5] = pk_bf16(g2.z, g2.w);
            u[6] = pk_bf16(g3.x, g3.y); u[7] = pk_bf16(g3.z, g3.w);
            __builtin_memcpy(&Pt[o_l][cp + 16 * j], u, 32);
        }
    }
    __syncthreads();

    floatx4 acc[4] = {};
    #pragma unroll
    for (int cc = 0; cc < 8; ++cc) {
        const int c0 = cc * 32 + quad * 8;
        const short8 a = *reinterpret_cast<const short8*>(&Pt[wave * 16 + l16][c0]);
        #pragma unroll
        for (int t4 = 0; t4 < 4; ++t4) {
            const short8 b = *reinterpret_cast<const short8*>(
                ao + (size_t)(n0 + t4 * 16 + l16) * 256 + c0);
            acc[t4] = __builtin_amdgcn_mfma_f32_16x16x32_bf16(a, b, acc[t4], 0, 0, 0);
        }
    }
    #pragma unroll
    for (int t4 = 0; t4 < 4; ++t4) {
        #pragma unroll
        for (int r = 0; r < 4; ++r) {
            const int o = m0 + wave * 16 + quad * 4 + r;
            const int n = n0 + t4 * 16 + l16;
            out[(size_t)o * 4096 + n] = acc[t4][r] + pb[o];
        }
    }
}

extern "C" void kernel_launch(void* const* d_in, const int* in_sizes, int n_in,
                              void* d_out, int out_size, void* d_ws, size_t ws_size,
                              hipStream_t stream) {
    const float* x      = (const float*)d_in[0];
    const float* qkv_w  = (const float*)d_in[1];
    const float* proj_w = (const float*)d_in[2];
    const float* proj_b = (const float*)d_in[3];
    float* out = (float*)d_out;                    // [256,4096] fp32

    char* B = (char*)d_ws;
    const size_t MB = 1u << 20;
    unsigned short* ao = (unsigned short*)(B);
    unsigned short* qm = (unsigned short*)(B + 2 * MB);
    unsigned short* km = (unsigned short*)(B + 4 * MB);
    unsigned short* vt = (unsigned short*)(B + 6 * MB);

    k_qkv<<<dim3(64, 12), 256, 0, stream>>>(x, qkv_w, qm, km, vt);
    k_attn<<<dim3(256, 8), 256, 0, stream>>>(qm, km, vt, ao);
    k_proj<<<dim3(64, 4), 256, 0, stream>>>(ao, proj_w, proj_b, out);
}

// Round 17
// 163.779 us; speedup vs baseline: 1.1505x; 1.0178x over previous
//
#include <hip/hip_runtime.h>
#include <hip/hip_bf16.h>

typedef __attribute__((ext_vector_type(8))) short short8;
typedef __attribute__((ext_vector_type(8))) unsigned short ushort8;
typedef __attribute__((ext_vector_type(4))) float floatx4;

#define L2E 1.4426950408889634f

#if __has_builtin(__builtin_amdgcn_exp2f)
#define EXP2(x) __builtin_amdgcn_exp2f(x)
#else
#define EXP2(x) exp2f(x)
#endif
#if __has_builtin(__builtin_amdgcn_rcpf)
#define RCP(x) __builtin_amdgcn_rcpf(x)
#else
#define RCP(x) (1.0f / (x))
#endif

static __device__ __forceinline__ unsigned short f2bf(float f) {
    unsigned int u = __builtin_bit_cast(unsigned int, f);
    u += 0x7fffu + ((u >> 16) & 1u);   // RNE
    return (unsigned short)(u >> 16);
}
static __device__ __forceinline__ unsigned int pk_bf16(float a, float b) {
    __hip_bfloat162 h2 = __float22bfloat162_rn(make_float2(a, b));   // v_cvt_pk_bf16_f32
    unsigned int u;
    __builtin_memcpy(&u, &h2, 4);     // low16 = a, high16 = b
    return u;
}

// ---------------- 1) QKV GEMM, self-staging (unchanged from R15) ----------------
__global__ __launch_bounds__(256) void k_qkv(const float* __restrict__ x,
                                             const float* __restrict__ qw,
                                             unsigned short* __restrict__ qm,
                                             unsigned short* __restrict__ km,
                                             unsigned short* __restrict__ vt) {
    __shared__ __align__(16) unsigned short At[64][136];
    __shared__ __align__(16) unsigned short Wt[64][136];
    const int tid = threadIdx.x;
    const int wave = tid >> 6, lane = tid & 63;
    const int l16 = lane & 15, quad = lane >> 4;
    const int m0 = blockIdx.x * 64;
    const int o0 = blockIdx.y * 64;

    floatx4 acc[4] = {};
    for (int rnd = 0; rnd < 2; ++rnd) {
        const int cbase = rnd * 128;
        if (rnd) __syncthreads();
        {
            const int moff = (tid & 3) * 16;
            #pragma unroll
            for (int half = 0; half < 2; ++half) {
                const int c_l = (tid >> 2) + 64 * half;
                const float4* xp = reinterpret_cast<const float4*>(
                    x + (size_t)(cbase + c_l) * 4096 + m0 + moff);
                const float4 f0 = xp[0], f1 = xp[1], f2 = xp[2], f3 = xp[3];
                At[moff +  0][c_l] = f2bf(f0.x); At[moff +  1][c_l] = f2bf(f0.y);
                At[moff +  2][c_l] = f2bf(f0.z); At[moff +  3][c_l] = f2bf(f0.w);
                At[moff +  4][c_l] = f2bf(f1.x); At[moff +  5][c_l] = f2bf(f1.y);
                At[moff +  6][c_l] = f2bf(f1.z); At[moff +  7][c_l] = f2bf(f1.w);
                At[moff +  8][c_l] = f2bf(f2.x); At[moff +  9][c_l] = f2bf(f2.y);
                At[moff + 10][c_l] = f2bf(f2.z); At[moff + 11][c_l] = f2bf(f2.w);
                At[moff + 12][c_l] = f2bf(f3.x); At[moff + 13][c_l] = f2bf(f3.y);
                At[moff + 14][c_l] = f2bf(f3.z); At[moff + 15][c_l] = f2bf(f3.w);
            }
        }
        {
            const int o_l = tid >> 2, cp = (tid & 3) * 32;
            const float4* wp = reinterpret_cast<const float4*>(
                qw + (size_t)(o0 + o_l) * 256 + cbase + cp);
            #pragma unroll
            for (int j = 0; j < 2; ++j) {
                const float4 g0 = wp[4 * j + 0], g1 = wp[4 * j + 1];
                const float4 g2 = wp[4 * j + 2], g3 = wp[4 * j + 3];
                unsigned int u[8];
                u[0] = pk_bf16(g0.x, g0.y); u[1] = pk_bf16(g0.z, g0.w);
                u[2] = pk_bf16(g1.x, g1.y); u[3] = pk_bf16(g1.z, g1.w);
                u[4] = pk_bf16(g2.x, g2.y); u[5] = pk_bf16(g2.z, g2.w);
                u[6] = pk_bf16(g3.x, g3.y); u[7] = pk_bf16(g3.z, g3.w);
                __builtin_memcpy(&Wt[o_l][cp + 16 * j], u, 32);
            }
        }
        __syncthreads();
        #pragma unroll
        for (int cc = 0; cc < 4; ++cc) {
            const int c0 = cc * 32 + quad * 8;
            const short8 a = *reinterpret_cast<const short8*>(&At[wave * 16 + l16][c0]);
            #pragma unroll
            for (int t4 = 0; t4 < 4; ++t4) {
                const short8 b = *reinterpret_cast<const short8*>(&Wt[t4 * 16 + l16][c0]);
                acc[t4] = __builtin_amdgcn_mfma_f32_16x16x32_bf16(a, b, acc[t4], 0, 0, 0);
            }
        }
    }
    const float qscale = 0.17677669529663687f * L2E;
    #pragma unroll
    for (int t4 = 0; t4 < 4; ++t4) {
        #pragma unroll
        for (int r = 0; r < 4; ++r) {
            const int n = m0 + wave * 16 + quad * 4 + r;
            const int o = o0 + t4 * 16 + l16;
            const int s = o >> 8, rem = o & 255, head = rem >> 5, t = rem & 31;
            if (s == 0)       qm[((size_t)head * 4096 + n) * 32 + t] = f2bf(acc[t4][r] * qscale);
            else if (s == 1)  km[((size_t)head * 4096 + n) * 32 + t] = f2bf(acc[t4][r]);
            else              vt[((size_t)head * 32 + t) * 4096 + n] = f2bf(acc[t4][r]);
        }
    }
}

// ---------------- 2) flash attention: S^T form, double-buffered PT (stride 72), deferred-PV ----------------
// block = 16 queries x 1 head; 4 waves split live key tiles; no atomics; ao bf16 [n][256].
// Per-wave smem region (4608 B) holds PT[2][16][72] during the loop, then is reused
// for obuf[32][20]+lbuf[16] after the wave's own loop ends (no cross-wave hazard:
// epilogue reads occur after __syncthreads).
__global__ __launch_bounds__(256) void k_attn(const unsigned short* __restrict__ qm,
                                              const unsigned short* __restrict__ km,
                                              const unsigned short* __restrict__ vt,
                                              unsigned short* __restrict__ ao) {
    const int h   = blockIdx.y;
    const int nq0 = blockIdx.x * 16;
    const int tid = threadIdx.x;
    const int wv  = __builtin_amdgcn_readfirstlane(tid >> 6);   // scalar: scan stays SALU
    const int lane = tid & 63;
    const int l16 = lane & 15, quad = lane >> 4;

    __shared__ __align__(16) char smem[4][4608];
    typedef unsigned short ptrow_t[16][72];   // one PT buffer: 16 q-rows x 72 (2304 B)
    ptrow_t* PTw = reinterpret_cast<ptrow_t*>(smem[wv]);        // PTw[buf][q][key]

    // B-operand for S^T: Q^T (n=q on l16, k=c on quad*8+j)
    const short8 a_q = *reinterpret_cast<const short8*>(
        qm + ((size_t)h * 4096 + nq0 + l16) * 32 + quad * 8);

    const int hq = (nq0 >> 4) & 15, dq = nq0 >> 8;
    float dw2[4];
    #pragma unroll
    for (int r = 0; r < 4; ++r) {
        const float dw = (float)(quad * 4 + r - l16);   // key_w - q_w (symmetric form)
        dw2[r] = dw * dw;
    }

    const unsigned short* kmh = km + ((size_t)h << 17) + l16 * 32 + quad * 8;
    const unsigned short* vt0 = vt + ((size_t)(h * 32 + l16) << 12) + quad * 8;
    const unsigned short* vt1 = vt0 + (16 << 12);

    float l_acc = 0.f;
    floatx4 o_acc[2] = {};

    int jt = -1, c = 0;

#define SCAN(J0, THR)                                                     \
    J0 = -1;                                                              \
    while (++jt < 64) {                                                   \
        const int dk = jt >> 2, hk0 = (jt & 3) * 4;                       \
        const int dd = dq - dk;                                           \
        int dh = 0;                                                       \
        if (hq < hk0) dh = hk0 - hq;                                      \
        else if (hq > hk0 + 3) dh = hq - hk0 - 3;                         \
        if (dd * dd + dh * dh >= 100) continue;                           \
        if (((c++) & 3) != wv) continue;                                  \
        J0 = jt * 64;                                                     \
        const int bb = 100 - dd * dd;                                     \
        THR[0] = bb - (hq - hk0) * (hq - hk0);                            \
        THR[1] = bb - (hq - hk0 - 1) * (hq - hk0 - 1);                    \
        THR[2] = bb - (hq - hk0 - 2) * (hq - hk0 - 2);                    \
        THR[3] = bb - (hq - hk0 - 3) * (hq - hk0 - 3);                    \
        break;                                                            \
    }

// S/exp/PT-write stage for tile (THR,KB) into buffer BUF
#define SSTAGE(THR, KB, BUF)                                              \
    {                                                                     \
        _Pragma("unroll")                                                 \
        for (int t4 = 0; t4 < 4; ++t4) {                                  \
            const bool sib = (THR[t4 ^ 1] > 0);                           \
            if (THR[t4] > 0) {                                            \
                const floatx4 sf = __builtin_amdgcn_mfma_f32_16x16x32_bf16( \
                    KB[t4], a_q, (floatx4){0.f, 0.f, 0.f, 0.f}, 0, 0, 0); \
                const float thrf = (float)THR[t4];                        \
                const float p0 = (dw2[0] < thrf) ? EXP2(sf[0]) : 0.f;     \
                const float p1 = (dw2[1] < thrf) ? EXP2(sf[1]) : 0.f;     \
                const float p2 = (dw2[2] < thrf) ? EXP2(sf[2]) : 0.f;     \
                const float p3 = (dw2[3] < thrf) ? EXP2(sf[3]) : 0.f;     \
                l_acc += (p0 + p1) + (p2 + p3);                           \
                unsigned int pair[2];                                     \
                pair[0] = pk_bf16(p0, p1);                                \
                pair[1] = pk_bf16(p2, p3);                                \
                __builtin_memcpy(&PTw[BUF][l16][t4 * 16 + quad * 4], pair, 8); \
            } else if (sib) {                                             \
                const unsigned int zz[2] = {0u, 0u};                      \
                __builtin_memcpy(&PTw[BUF][l16][t4 * 16 + quad * 4], zz, 8); \
            }                                                             \
        }                                                                 \
    }

    // ---- prologue: first live tile -> S stage into buf 0 ----
    int j0p, thrp[4];           // "prev": PT written, PV pending
    SCAN(j0p, thrp)
    if (j0p >= 0) {
        short8 kprev[4];
        #pragma unroll
        for (int t4 = 0; t4 < 4; ++t4)
            kprev[t4] = *reinterpret_cast<const short8*>(kmh + ((j0p + t4 * 16) << 5));
        SSTAGE(thrp, kprev, 0)
    }

    int j0c, thrc[4];           // "cur": K loaded, S pending
    SCAN(j0c, thrc)
    short8 kb[4];
    if (j0c >= 0) {
        #pragma unroll
        for (int t4 = 0; t4 < 4; ++t4)
            kb[t4] = *reinterpret_cast<const short8*>(kmh + ((j0c + t4 * 16) << 5));
    }

    int pb = 0;                 // buffer holding prev's P
    while (j0p >= 0) {
        // V(prev): issue now, consumed after S(cur)/exp (~latency hidden)
        const short8 v00 = *reinterpret_cast<const short8*>(vt0 + j0p);
        const short8 v01 = *reinterpret_cast<const short8*>(vt1 + j0p);
        const short8 v10 = *reinterpret_cast<const short8*>(vt0 + j0p + 32);
        const short8 v11 = *reinterpret_cast<const short8*>(vt1 + j0p + 32);

        // S stage for cur into the other buffer (independent of PV(prev))
        if (j0c >= 0) SSTAGE(thrc, kb, pb ^ 1)

        // scan + K-load for next (hidden across this iteration)
        int j0n, thrn[4];
        SCAN(j0n, thrn)
        short8 kn[4];
        if (j0n >= 0) {
            #pragma unroll
            for (int t4 = 0; t4 < 4; ++t4)
                kn[t4] = *reinterpret_cast<const short8*>(kmh + ((j0n + t4 * 16) << 5));
        }

        // PV(prev) from PT[pb]
        #pragma unroll
        for (int kt = 0; kt < 2; ++kt) {
            if (thrp[2 * kt] <= 0 && thrp[2 * kt + 1] <= 0) continue;
            const short8 b_p = *reinterpret_cast<const short8*>(
                &PTw[pb][l16][kt * 32 + quad * 8]);
            o_acc[0] = __builtin_amdgcn_mfma_f32_16x16x32_bf16(
                kt ? v10 : v00, b_p, o_acc[0], 0, 0, 0);
            o_acc[1] = __builtin_amdgcn_mfma_f32_16x16x32_bf16(
                kt ? v11 : v01, b_p, o_acc[1], 0, 0, 0);
        }

        // rotate pipeline
        j0p = j0c;
        #pragma unroll
        for (int t4 = 0; t4 < 4; ++t4) { thrp[t4] = thrc[t4]; kb[t4] = kn[t4]; thrc[t4] = thrn[t4]; }
        j0c = j0n;
        pb ^= 1;
    }
#undef SSTAGE
#undef SCAN

    // ---- epilogue: reuse this wave's smem region for O/l partials ----
    float (*obufw)[20] = reinterpret_cast<float(*)[20]>(smem[wv]);   // [32][20], 2560 B
    float* lbufw = reinterpret_cast<float*>(smem[wv] + 2560);        // [16]

    // l: per-lane scalar; sum over quads (lanes sharing l16)
    l_acc += __shfl_xor(l_acc, 16);
    l_acc += __shfl_xor(l_acc, 32);
    if (lane < 16) lbufw[l16] = l_acc;
    #pragma unroll
    for (int tt = 0; tt < 2; ++tt)
        #pragma unroll
        for (int r = 0; r < 4; ++r)
            obufw[tt * 16 + quad * 4 + r][l16] = o_acc[tt][r];
    __syncthreads();

    // combine waves, normalize, write (q = tid&15, d pair = (tid>>4)*2)
    const int q = tid & 15, d0 = (tid >> 4) * 2;
    float lt = 0.f, oa = 0.f, ob = 0.f;
    #pragma unroll
    for (int w = 0; w < 4; ++w) {
        const float (*obw)[20] = reinterpret_cast<const float(*)[20]>(smem[w]);
        lt += reinterpret_cast<const float*>(smem[w] + 2560)[q];
        oa += obw[d0][q];
        ob += obw[d0 + 1][q];
    }
    const float inv = RCP(lt);
    const unsigned int uo = pk_bf16(oa * inv, ob * inv);
    *reinterpret_cast<unsigned int*>(ao + (size_t)(nq0 + q) * 256 + h * 32 + d0) = uo;
}

// ---------------- 3) proj GEMM + bias, self-staging pw (unchanged from R15) ----------------
__global__ __launch_bounds__(256) void k_proj(const unsigned short* __restrict__ ao,
                                              const float* __restrict__ pw,
                                              const float* __restrict__ pb,
                                              float* __restrict__ out) {
    __shared__ __align__(16) unsigned short Pt[64][264];
    const int tid = threadIdx.x;
    const int wave = tid >> 6, lane = tid & 63;
    const int l16 = lane & 15, quad = lane >> 4;
    const int n0 = blockIdx.x * 64;
    const int m0 = blockIdx.y * 64;

    {
        const int o_l = tid >> 2, cp = (tid & 3) * 64;
        const float4* wp = reinterpret_cast<const float4*>(pw + (size_t)(m0 + o_l) * 256 + cp);
        #pragma unroll
        for (int j = 0; j < 4; ++j) {
            const float4 g0 = wp[4 * j + 0], g1 = wp[4 * j + 1];
            const float4 g2 = wp[4 * j + 2], g3 = wp[4 * j + 3];
            unsigned int u[8];
            u[0] = pk_bf16(g0.x, g0.y); u[1] = pk_bf16(g0.z, g0.w);
            u[2] = pk_bf16(g1.x, g1.y); u[3] = pk_bf16(g1.z, g1.w);
            u[4] = pk_bf16(g2.x, g2.y); u[5] = pk_bf16(g2.z, g2.w);
            u[6] = pk_bf16(g3.x, g3.y); u[7] = pk_bf16(g3.z, g3.w);
            __builtin_memcpy(&Pt[o_l][cp + 16 * j], u, 32);
        }
    }
    __syncthreads();

    floatx4 acc[4] = {};
    #pragma unroll
    for (int cc = 0; cc < 8; ++cc) {
        const int c0 = cc * 32 + quad * 8;
        const short8 a = *reinterpret_cast<const short8*>(&Pt[wave * 16 + l16][c0]);
        #pragma unroll
        for (int t4 = 0; t4 < 4; ++t4) {
            const short8 b = *reinterpret_cast<const short8*>(
                ao + (size_t)(n0 + t4 * 16 + l16) * 256 + c0);
            acc[t4] = __builtin_amdgcn_mfma_f32_16x16x32_bf16(a, b, acc[t4], 0, 0, 0);
        }
    }
    #pragma unroll
    for (int t4 = 0; t4 < 4; ++t4) {
        #pragma unroll
        for (int r = 0; r < 4; ++r) {
            const int o = m0 + wave * 16 + quad * 4 + r;
            const int n = n0 + t4 * 16 + l16;
            out[(size_t)o * 4096 + n] = acc[t4][r] + pb[o];
        }
    }
}

extern "C" void kernel_launch(void* const* d_in, const int* in_sizes, int n_in,
                              void* d_out, int out_size, void* d_ws, size_t ws_size,
                              hipStream_t stream) {
    const float* x      = (const float*)d_in[0];
    const float* qkv_w  = (const float*)d_in[1];
    const float* proj_w = (const float*)d_in[2];
    const float* proj_b = (const float*)d_in[3];
    float* out = (float*)d_out;                    // [256,4096] fp32

    char* B = (char*)d_ws;
    const size_t MB = 1u << 20;
    unsigned short* ao = (unsigned short*)(B);
    unsigned short* qm = (unsigned short*)(B + 2 * MB);
    unsigned short* km = (unsigned short*)(B + 4 * MB);
    unsigned short* vt = (unsigned short*)(B + 6 * MB);

    k_qkv<<<dim3(64, 12), 256, 0, stream>>>(x, qkv_w, qm, km, vt);
    k_attn<<<dim3(256, 8), 256, 0, stream>>>(qm, km, vt, ao);
    k_proj<<<dim3(64, 4), 256, 0, stream>>>(ao, proj_w, proj_b, out);
}